// Round 1
// baseline (2016.094 us; speedup 1.0000x reference)
//
#include <hip/hip_runtime.h>
#include <hip/hip_bf16.h>
#include <math.h>

// Problem constants
#define BATCH   2
#define SEQ     2048
#define DMODEL  1024
#define NHEADS  16
#define DK      64
#define MROWS   (BATCH * SEQ)          // 4096
#define OUT0_ELEMS ((size_t)BATCH * SEQ * DMODEL)            // 4,194,304
// attn weights: B*H*S*S = 134,217,728 elems

// ---------------------------------------------------------------------------
// Generic tiled GEMM: C[m,n] = sum_k A[m,k] * Bw[n,k] + bias[n]
// A: M x K row-major ; Bw: N x K row-major (i.e. we compute A @ Bw^T + bias)
// BM=BN=64, BK=16, 256 threads, 4x4 micro-tile per thread.
// ---------------------------------------------------------------------------
__global__ __launch_bounds__(256) void gemm_abt(const float* __restrict__ A,
                                                const float* __restrict__ Bw,
                                                const float* __restrict__ bias,
                                                float* __restrict__ C,
                                                int M, int N, int K)
{
    __shared__ float As[64][17];
    __shared__ float Bs[64][17];

    const int tid = threadIdx.x;
    const int m0 = blockIdx.y * 64;
    const int n0 = blockIdx.x * 64;
    const int tx = tid & 15;       // 0..15
    const int ty = tid >> 4;       // 0..15

    float acc[4][4] = {};

    const int lr = tid >> 2;          // 0..63 (row within tile)
    const int lc = (tid & 3) * 4;     // 0,4,8,12

    for (int k0 = 0; k0 < K; k0 += 16) {
        float4 av = *(const float4*)(A  + (size_t)(m0 + lr) * K + k0 + lc);
        float4 bv = *(const float4*)(Bw + (size_t)(n0 + lr) * K + k0 + lc);
        As[lr][lc+0] = av.x; As[lr][lc+1] = av.y; As[lr][lc+2] = av.z; As[lr][lc+3] = av.w;
        Bs[lr][lc+0] = bv.x; Bs[lr][lc+1] = bv.y; Bs[lr][lc+2] = bv.z; Bs[lr][lc+3] = bv.w;
        __syncthreads();
#pragma unroll
        for (int kk = 0; kk < 16; ++kk) {
            float a[4], b[4];
#pragma unroll
            for (int i = 0; i < 4; ++i) a[i] = As[ty*4+i][kk];
#pragma unroll
            for (int j = 0; j < 4; ++j) b[j] = Bs[tx*4+j][kk];
#pragma unroll
            for (int i = 0; i < 4; ++i)
#pragma unroll
                for (int j = 0; j < 4; ++j)
                    acc[i][j] += a[i] * b[j];
        }
        __syncthreads();
    }

#pragma unroll
    for (int i = 0; i < 4; ++i) {
        int m = m0 + ty*4 + i;
#pragma unroll
        for (int j = 0; j < 4; ++j) {
            int n = n0 + tx*4 + j;
            C[(size_t)m * N + n] = acc[i][j] + bias[n];
        }
    }
}

// ---------------------------------------------------------------------------
// Scores: P[b,h,q,k] = (Q[b,q,h*64:...] . K[b,k,h*64:...]) / 8
// Q,K stored as (B*S, DMODEL) row-major. Grid: (S/64, S/64, B*H).
// ---------------------------------------------------------------------------
__global__ __launch_bounds__(256) void scores_kernel(const float* __restrict__ Q,
                                                     const float* __restrict__ Km,
                                                     float* __restrict__ P)
{
    const int bh = blockIdx.z;
    const int b  = bh >> 4;
    const int h  = bh & 15;
    const int q0 = blockIdx.y * 64;
    const int k0 = blockIdx.x * 64;

    __shared__ float Qs[64][65];
    __shared__ float Ks[64][65];

    const int tid = threadIdx.x;
    const int tx = tid & 15;
    const int ty = tid >> 4;

    // load 64x64 tiles (4 float4 per thread each)
#pragma unroll
    for (int it = 0; it < 4; ++it) {
        int r = (tid >> 4) + it * 16;
        int c = (tid & 15) * 4;
        float4 qv = *(const float4*)(Q  + (size_t)(b*SEQ + q0 + r) * DMODEL + h*DK + c);
        float4 kv = *(const float4*)(Km + (size_t)(b*SEQ + k0 + r) * DMODEL + h*DK + c);
        Qs[r][c+0]=qv.x; Qs[r][c+1]=qv.y; Qs[r][c+2]=qv.z; Qs[r][c+3]=qv.w;
        Ks[r][c+0]=kv.x; Ks[r][c+1]=kv.y; Ks[r][c+2]=kv.z; Ks[r][c+3]=kv.w;
    }
    __syncthreads();

    float acc[4][4] = {};
#pragma unroll 8
    for (int kk = 0; kk < 64; ++kk) {
        float a[4], bb[4];
#pragma unroll
        for (int i = 0; i < 4; ++i) a[i]  = Qs[ty*4+i][kk];
#pragma unroll
        for (int j = 0; j < 4; ++j) bb[j] = Ks[tx*4+j][kk];
#pragma unroll
        for (int i = 0; i < 4; ++i)
#pragma unroll
            for (int j = 0; j < 4; ++j)
                acc[i][j] += a[i] * bb[j];
    }

#pragma unroll
    for (int i = 0; i < 4; ++i) {
        size_t row = (size_t)bh * SEQ + q0 + ty*4 + i;
#pragma unroll
        for (int j = 0; j < 4; ++j) {
            P[row * SEQ + k0 + tx*4 + j] = acc[i][j] * 0.125f;
        }
    }
}

// ---------------------------------------------------------------------------
// Row softmax in place over rows of length SEQ (2048). One block (256 thr) per row.
// ---------------------------------------------------------------------------
__global__ __launch_bounds__(256) void softmax_kernel(float* __restrict__ P)
{
    __shared__ float red[256];
    const int tid = threadIdx.x;
    float* row = P + (size_t)blockIdx.x * SEQ;

    float v[8];
    float m = -INFINITY;
#pragma unroll
    for (int t = 0; t < 8; ++t) {
        v[t] = row[tid + t * 256];
        m = fmaxf(m, v[t]);
    }
    red[tid] = m;
    __syncthreads();
    for (int s = 128; s > 0; s >>= 1) {
        if (tid < s) red[tid] = fmaxf(red[tid], red[tid + s]);
        __syncthreads();
    }
    const float rowmax = red[0];
    __syncthreads();

    float sum = 0.f;
#pragma unroll
    for (int t = 0; t < 8; ++t) {
        v[t] = expf(v[t] - rowmax);
        sum += v[t];
    }
    red[tid] = sum;
    __syncthreads();
    for (int s = 128; s > 0; s >>= 1) {
        if (tid < s) red[tid] += red[tid + s];
        __syncthreads();
    }
    const float inv = 1.0f / red[0];

#pragma unroll
    for (int t = 0; t < 8; ++t) {
        row[tid + t * 256] = v[t] * inv;
    }
}

// ---------------------------------------------------------------------------
// Context: ctx[b, q, h*64+d] = sum_k P[b,h,q,k] * V[b,k,h*64+d]
// Per (b,h): M=2048 (q) x N=64 (d), K=2048. Grid: (1, S/64, B*H). BK=32.
// ---------------------------------------------------------------------------
__global__ __launch_bounds__(256) void context_kernel(const float* __restrict__ P,
                                                      const float* __restrict__ V,
                                                      float* __restrict__ ctx)
{
    const int bh = blockIdx.z;
    const int b  = bh >> 4;
    const int h  = bh & 15;
    const int q0 = blockIdx.y * 64;

    __shared__ float Ps[64][33];
    __shared__ float Vs[32][65];

    const int tid = threadIdx.x;
    const int tx = tid & 15;
    const int ty = tid >> 4;

    float acc[4][4] = {};

    for (int k0 = 0; k0 < SEQ; k0 += 32) {
        // P tile: 64 rows x 32 cols -> 512 float4, 2 per thread
#pragma unroll
        for (int it = 0; it < 2; ++it) {
            int r = (tid >> 3) + it * 32;      // 0..63
            int c = (tid & 7) * 4;             // 0..28
            float4 pv = *(const float4*)(P + ((size_t)bh * SEQ + q0 + r) * SEQ + k0 + c);
            Ps[r][c+0]=pv.x; Ps[r][c+1]=pv.y; Ps[r][c+2]=pv.z; Ps[r][c+3]=pv.w;
        }
        // V tile: 32 rows x 64 cols -> 512 float4, 2 per thread
#pragma unroll
        for (int it = 0; it < 2; ++it) {
            int r = (tid >> 4) + it * 16;      // 0..31
            int c = (tid & 15) * 4;            // 0..60
            float4 vv = *(const float4*)(V + (size_t)(b*SEQ + k0 + r) * DMODEL + h*DK + c);
            Vs[r][c+0]=vv.x; Vs[r][c+1]=vv.y; Vs[r][c+2]=vv.z; Vs[r][c+3]=vv.w;
        }
        __syncthreads();
#pragma unroll 8
        for (int kk = 0; kk < 32; ++kk) {
            float a[4], bb[4];
#pragma unroll
            for (int i = 0; i < 4; ++i) a[i]  = Ps[ty*4+i][kk];
#pragma unroll
            for (int j = 0; j < 4; ++j) bb[j] = Vs[kk][tx*4+j];
#pragma unroll
            for (int i = 0; i < 4; ++i)
#pragma unroll
                for (int j = 0; j < 4; ++j)
                    acc[i][j] += a[i] * bb[j];
        }
        __syncthreads();
    }

#pragma unroll
    for (int i = 0; i < 4; ++i) {
        int q = q0 + ty*4 + i;
#pragma unroll
        for (int j = 0; j < 4; ++j) {
            int d = tx*4 + j;
            ctx[(size_t)(b*SEQ + q) * DMODEL + h*DK + d] = acc[i][j];
        }
    }
}

// ---------------------------------------------------------------------------
extern "C" void kernel_launch(void* const* d_in, const int* in_sizes, int n_in,
                              void* d_out, int out_size, void* d_ws, size_t ws_size,
                              hipStream_t stream)
{
    const float* query = (const float*)d_in[0];
    const float* key   = (const float*)d_in[1];
    const float* value = (const float*)d_in[2];
    const float* Wq    = (const float*)d_in[3];
    const float* bq    = (const float*)d_in[4];
    const float* Wk    = (const float*)d_in[5];
    const float* bk    = (const float*)d_in[6];
    const float* Wv    = (const float*)d_in[7];
    const float* bv    = (const float*)d_in[8];
    const float* Wo    = (const float*)d_in[9];
    const float* bo    = (const float*)d_in[10];

    float* out  = (float*)d_out;                 // (B,S,DMODEL)
    float* attn = (float*)d_out + OUT0_ELEMS;    // (B,H,S,S)

    // workspace: Q, K, V, ctx each MROWS*DMODEL floats (16 MiB) = 64 MiB total
    float* Qb  = (float*)d_ws;
    float* Kb  = Qb + (size_t)MROWS * DMODEL;
    float* Vb  = Kb + (size_t)MROWS * DMODEL;
    float* Cb  = Vb + (size_t)MROWS * DMODEL;

    dim3 gGemm(DMODEL / 64, MROWS / 64);   // (16, 64)
    dim3 tBlk(256);

    // Q/K/V projections
    hipLaunchKernelGGL(gemm_abt, gGemm, tBlk, 0, stream, query, Wq, bq, Qb, MROWS, DMODEL, DMODEL);
    hipLaunchKernelGGL(gemm_abt, gGemm, tBlk, 0, stream, key,   Wk, bk, Kb, MROWS, DMODEL, DMODEL);
    hipLaunchKernelGGL(gemm_abt, gGemm, tBlk, 0, stream, value, Wv, bv, Vb, MROWS, DMODEL, DMODEL);

    // scores -> attn region (raw)
    dim3 gScore(SEQ / 64, SEQ / 64, BATCH * NHEADS);  // (32,32,32)
    hipLaunchKernelGGL(scores_kernel, gScore, tBlk, 0, stream, Qb, Kb, attn);

    // softmax in place
    dim3 gSm(BATCH * NHEADS * SEQ);                   // 65536
    hipLaunchKernelGGL(softmax_kernel, gSm, tBlk, 0, stream, attn);

    // context
    dim3 gCtx(1, SEQ / 64, BATCH * NHEADS);           // (1,32,32)
    hipLaunchKernelGGL(context_kernel, gCtx, tBlk, 0, stream, attn, Vb, Cb);

    // output projection
    hipLaunchKernelGGL(gemm_abt, gGemm, tBlk, 0, stream, Cb, Wo, bo, out, MROWS, DMODEL, DMODEL);
}